// Round 1
// baseline (253.266 us; speedup 1.0000x reference)
//
#include <hip/hip_runtime.h>

// ScaledDotProductAttention: causal, L2-normalized Q/K (cosine attention)
// B=4 H=16 N=2048 D=64, fp32 in/out, bf16 MFMA compute.
//
// Pipeline:
//  1) norm_rows:  Qn = bf16(Q / (||Q||+eps) * g[h]),  Kn = bf16(K / (||K||+eps))
//  2) transpose_v: Vt[b][h][d][n] = bf16(V[b][h][n][d])
//  3) attn_fwd:   flash-attention, Q-tile 64 (4 waves x 16 rows), K-tile 64,
//                 mfma_f32_16x16x32_bf16, online softmax, fp32 out.

#define BATCH 4
#define HEADS 16
#define SEQ   2048
#define DIM   64
#define EPS   1e-8f
#define LOG2E 1.44269504088896340736f

typedef short bf16x8 __attribute__((ext_vector_type(8)));
typedef short s16x4  __attribute__((ext_vector_type(4)));
typedef float fx4    __attribute__((ext_vector_type(4)));

static __device__ __forceinline__ short f2bf(float x) {
    unsigned u = __float_as_uint(x);
    unsigned r = (u + 0x7fffu + ((u >> 16) & 1u)) >> 16;   // RNE
    return (short)r;
}

// ---------------------------------------------------------------------------
// Kernel 1: row L2-normalize Q (scaled by g[h]) and K into bf16.
// One 16-lane group per row (4 floats/lane). 16 rows per 256-thread block.
// Rows [0, R) = Q, rows [R, 2R) = K.
// ---------------------------------------------------------------------------
__global__ __launch_bounds__(256) void norm_rows(
    const float* __restrict__ Q, const float* __restrict__ K,
    const float* __restrict__ scale,
    short* __restrict__ Qn, short* __restrict__ Kn)
{
    const int tid  = threadIdx.x;
    const int lane = tid & 63;
    const long long R = (long long)BATCH * HEADS * SEQ;
    long long rid = (long long)blockIdx.x * 16 + (tid >> 6) * 4 + (lane >> 4);
    const int c4 = (lane & 15) * 4;

    const float* src;
    short* dst;
    float g;
    if (rid < R) {
        src = Q + rid * DIM;
        dst = Qn + rid * DIM;
        g = scale[(int)((rid >> 11) & (HEADS - 1))];   // h = (rid/N)%H
    } else {
        long long r2 = rid - R;
        src = K + r2 * DIM;
        dst = Kn + r2 * DIM;
        g = 1.0f;
    }

    float4 v = *(const float4*)(src + c4);
    float ss = v.x * v.x + v.y * v.y + v.z * v.z + v.w * v.w;
    ss += __shfl_xor(ss, 1);
    ss += __shfl_xor(ss, 2);
    ss += __shfl_xor(ss, 4);
    ss += __shfl_xor(ss, 8);
    float s = g / (sqrtf(ss) + EPS);

    s16x4 o;
    o[0] = f2bf(v.x * s);
    o[1] = f2bf(v.y * s);
    o[2] = f2bf(v.z * s);
    o[3] = f2bf(v.w * s);
    *(s16x4*)(dst + c4) = o;
}

// ---------------------------------------------------------------------------
// Kernel 2: V [n][d] fp32 -> Vt [d][n] bf16, per (b,h), 64x64 tiles via LDS.
// ---------------------------------------------------------------------------
#define TLDS 68   // padded LDS stride (bf16 elems); 68*2=136 B keeps 8B align

__global__ __launch_bounds__(256) void transpose_v(
    const float* __restrict__ V, short* __restrict__ Vt)
{
    const int nt = blockIdx.x;          // n-tile
    const int bh = blockIdx.y;          // b*H+h
    const float* Vb = V + ((size_t)bh * SEQ + (size_t)nt * 64) * DIM;
    short* Vo = Vt + (size_t)bh * DIM * SEQ + (size_t)nt * 64;

    __shared__ short lds[DIM * TLDS];
    const int t  = threadIdx.x;
    const int cg = t & 15;
    const int rr = t >> 4;

#pragma unroll
    for (int i = 0; i < 4; ++i) {
        int n  = rr + i * 16;
        int d0 = cg * 4;
        float4 v = *(const float4*)(Vb + (size_t)n * DIM + d0);
        lds[(d0 + 0) * TLDS + n] = f2bf(v.x);
        lds[(d0 + 1) * TLDS + n] = f2bf(v.y);
        lds[(d0 + 2) * TLDS + n] = f2bf(v.z);
        lds[(d0 + 3) * TLDS + n] = f2bf(v.w);
    }
    __syncthreads();
#pragma unroll
    for (int i = 0; i < 4; ++i) {
        int d  = rr + i * 16;
        int nl = cg * 4;
        s16x4 o;
        o[0] = lds[d * TLDS + nl + 0];
        o[1] = lds[d * TLDS + nl + 1];
        o[2] = lds[d * TLDS + nl + 2];
        o[3] = lds[d * TLDS + nl + 3];
        *(s16x4*)(Vo + (size_t)d * SEQ + nl) = o;
    }
}

// ---------------------------------------------------------------------------
// Kernel 3: causal flash attention.
// Block = 256 threads (4 waves). Q-tile = 64 rows (wave w owns rows w*16..+15,
// Q A-frags in registers). K-tile = 64. LDS: K tile, Vt tile, P tile, all
// stride-padded to 72 elems (144 B) -> <=2-way bank conflicts on ds_read_b128.
//
// mfma_f32_16x16x32_bf16 layouts (guide-verified):
//   A: row = lane&15, k = (lane>>4)*8 + j
//   B: col = lane&15, k = (lane>>4)*8 + j
//   C/D: col = lane&15, row = (lane>>4)*4 + reg
// ---------------------------------------------------------------------------
#define LDK 72

__global__ __launch_bounds__(256) void attn_fwd(
    const short* __restrict__ Qn, const short* __restrict__ Kn,
    const short* __restrict__ Vt, float* __restrict__ out)
{
    const int qt  = (gridDim.x - 1) - blockIdx.x;   // heaviest blocks first
    const int bh  = blockIdx.y;
    const int tid = threadIdx.x;
    const int w   = tid >> 6;
    const int l   = tid & 63;
    const int q0  = qt * 64;
    const int lr  = l & 15;
    const int hg  = l >> 4;
    const int koff = hg * 8;

    const short* Qb = Qn + (size_t)bh * SEQ * DIM;
    const short* Kb = Kn + (size_t)bh * SEQ * DIM;
    const short* Vb = Vt + (size_t)bh * DIM * SEQ;

    __shared__ short lds_k[64 * LDK];
    __shared__ short lds_v[64 * LDK];
    __shared__ short lds_p[64 * LDK];

    // Q A-fragments for this wave's 16 rows (row = lr), k-chunks 0..31 / 32..63
    const size_t qrow = (size_t)(q0 + w * 16 + lr) * DIM;
    bf16x8 qf0 = *(const bf16x8*)(Qb + qrow + koff);
    bf16x8 qf1 = *(const bf16x8*)(Qb + qrow + 32 + koff);

    fx4 oacc[4];
    float mrow[4], lsum[4];
#pragma unroll
    for (int r = 0; r < 4; ++r) {
        oacc[r] = (fx4){0.f, 0.f, 0.f, 0.f};
        mrow[r] = -3.0e38f;
        lsum[r] = 0.f;
    }

    const int row0 = q0 + w * 16 + hg * 4;   // +reg = this lane's output rows
    const int nkt  = qt + 1;

    // staging coords: thread loads 8 bf16 (16B) x2 per tile
    const int sr = tid >> 3;          // 0..31
    const int sc = (tid & 7) * 8;     // 0..56

    for (int kt = 0; kt < nkt; ++kt) {
        const int k0 = kt * 64;
        __syncthreads();   // previous iteration's reads done before restage
        *(bf16x8*)(&lds_k[sr * LDK + sc]) =
            *(const bf16x8*)(Kb + (size_t)(k0 + sr) * DIM + sc);
        *(bf16x8*)(&lds_k[(sr + 32) * LDK + sc]) =
            *(const bf16x8*)(Kb + (size_t)(k0 + sr + 32) * DIM + sc);
        *(bf16x8*)(&lds_v[sr * LDK + sc]) =
            *(const bf16x8*)(Vb + (size_t)sr * SEQ + k0 + sc);
        *(bf16x8*)(&lds_v[(sr + 32) * LDK + sc]) =
            *(const bf16x8*)(Vb + (size_t)(sr + 32) * SEQ + k0 + sc);
        __syncthreads();

        // ---- S = Q K^T  (4 col-tiles of 16, 2 k-chunks) ----
        fx4 s[4];
#pragma unroll
        for (int ct = 0; ct < 4; ++ct) s[ct] = (fx4){0.f, 0.f, 0.f, 0.f};
#pragma unroll
        for (int ct = 0; ct < 4; ++ct) {
            bf16x8 kf0 = *(const bf16x8*)(&lds_k[(ct * 16 + lr) * LDK + koff]);
            bf16x8 kf1 = *(const bf16x8*)(&lds_k[(ct * 16 + lr) * LDK + 32 + koff]);
            s[ct] = __builtin_amdgcn_mfma_f32_16x16x32_bf16(qf0, kf0, s[ct], 0, 0, 0);
            s[ct] = __builtin_amdgcn_mfma_f32_16x16x32_bf16(qf1, kf1, s[ct], 0, 0, 0);
        }

        // ---- causal mask (tile overlaps diagonal for this wave) ----
        if (k0 + 63 > q0 + w * 16) {
#pragma unroll
            for (int ct = 0; ct < 4; ++ct) {
                int col = k0 + ct * 16 + lr;
#pragma unroll
                for (int r = 0; r < 4; ++r)
                    if (col > row0 + r) s[ct][r] = -3.0e38f;
            }
        }

        // ---- online softmax (rows live in 16-lane groups) ----
        float pmax[4];
#pragma unroll
        for (int r = 0; r < 4; ++r) {
            pmax[r] = fmaxf(fmaxf(s[0][r], s[1][r]), fmaxf(s[2][r], s[3][r]));
            pmax[r] = fmaxf(pmax[r], __shfl_xor(pmax[r], 1));
            pmax[r] = fmaxf(pmax[r], __shfl_xor(pmax[r], 2));
            pmax[r] = fmaxf(pmax[r], __shfl_xor(pmax[r], 4));
            pmax[r] = fmaxf(pmax[r], __shfl_xor(pmax[r], 8));
        }
        float rescale[4];
#pragma unroll
        for (int r = 0; r < 4; ++r) {
            float nm = fmaxf(mrow[r], pmax[r]);
            rescale[r] = __builtin_amdgcn_exp2f((mrow[r] - nm) * LOG2E);
            mrow[r] = nm;
        }
        float rs[4] = {0.f, 0.f, 0.f, 0.f};
#pragma unroll
        for (int ct = 0; ct < 4; ++ct) {
#pragma unroll
            for (int r = 0; r < 4; ++r) {
                float p = __builtin_amdgcn_exp2f((s[ct][r] - mrow[r]) * LOG2E);
                s[ct][r] = p;
                rs[r] += p;
            }
        }
#pragma unroll
        for (int r = 0; r < 4; ++r) {
            rs[r] += __shfl_xor(rs[r], 1);
            rs[r] += __shfl_xor(rs[r], 2);
            rs[r] += __shfl_xor(rs[r], 4);
            rs[r] += __shfl_xor(rs[r], 8);
            lsum[r] = lsum[r] * rescale[r] + rs[r];
        }
#pragma unroll
        for (int dt = 0; dt < 4; ++dt)
#pragma unroll
            for (int r = 0; r < 4; ++r) oacc[dt][r] *= rescale[r];

        // ---- P -> LDS (bf16), wave-private region, no barrier needed ----
#pragma unroll
        for (int ct = 0; ct < 4; ++ct)
#pragma unroll
            for (int r = 0; r < 4; ++r)
                lds_p[(w * 16 + hg * 4 + r) * LDK + ct * 16 + lr] = f2bf(s[ct][r]);

        // ---- O += P V  (A = P from LDS, B = Vt rows) ----
        bf16x8 pf0 = *(const bf16x8*)(&lds_p[(w * 16 + lr) * LDK + koff]);
        bf16x8 pf1 = *(const bf16x8*)(&lds_p[(w * 16 + lr) * LDK + 32 + koff]);
#pragma unroll
        for (int dt = 0; dt < 4; ++dt) {
            bf16x8 vf0 = *(const bf16x8*)(&lds_v[(dt * 16 + lr) * LDK + koff]);
            bf16x8 vf1 = *(const bf16x8*)(&lds_v[(dt * 16 + lr) * LDK + 32 + koff]);
            oacc[dt] = __builtin_amdgcn_mfma_f32_16x16x32_bf16(pf0, vf0, oacc[dt], 0, 0, 0);
            oacc[dt] = __builtin_amdgcn_mfma_f32_16x16x32_bf16(pf1, vf1, oacc[dt], 0, 0, 0);
        }
    }

    // ---- epilogue: out = O / l ----
#pragma unroll
    for (int r = 0; r < 4; ++r) {
        float inv = 1.0f / lsum[r];
        size_t base = ((size_t)bh * SEQ + (size_t)(row0 + r)) * DIM;
#pragma unroll
        for (int dt = 0; dt < 4; ++dt)
            out[base + dt * 16 + lr] = oacc[dt][r] * inv;
    }
}

// ---------------------------------------------------------------------------
extern "C" void kernel_launch(void* const* d_in, const int* in_sizes, int n_in,
                              void* d_out, int out_size, void* d_ws, size_t ws_size,
                              hipStream_t stream)
{
    const float* Q  = (const float*)d_in[0];
    const float* K  = (const float*)d_in[1];
    const float* V  = (const float*)d_in[2];
    const float* qs = (const float*)d_in[3];
    // d_in[4] = M (causal mask) — recomputed analytically, not read.
    float* out = (float*)d_out;

    const size_t nElem = (size_t)BATCH * HEADS * SEQ * DIM;   // 8388608
    short* Qn = (short*)d_ws;
    short* Kn = Qn + nElem;
    short* Vt = Kn + nElem;   // total ws use: 3 * 16.78 MB = 50.3 MB

    // 1) normalize Q and K (2*B*H*N rows, 16 rows/block)
    {
        long long rows = 2LL * BATCH * HEADS * SEQ;
        int blocks = (int)(rows / 16);
        norm_rows<<<blocks, 256, 0, stream>>>(Q, K, qs, Qn, Kn);
    }
    // 2) transpose V -> Vt bf16
    {
        dim3 grid(SEQ / 64, BATCH * HEADS);
        transpose_v<<<grid, 256, 0, stream>>>(V, Vt);
    }
    // 3) flash attention
    {
        dim3 grid(SEQ / 64, BATCH * HEADS);
        attn_fwd<<<grid, 256, 0, stream>>>(Qn, Kn, Vt, out);
    }
}

// Round 2
// 155.699 us; speedup vs baseline: 1.6266x; 1.6266x over previous
//
#include <hip/hip_runtime.h>

// ScaledDotProductAttention: causal cosine attention.
// B=4 H=16 N=2048 D=64, fp32 in/out, bf16 MFMA compute.
//
// Round 2: LDS-free swapped-operand flash attention.
//  - S' = mfma_32x32x16(A=K_frag, B=Q_frag): lane holds P[key-subset][q=lane&31]
//  - softmax fully in-register (tree + one shfl_xor(32)), defer-max THR=8
//  - P repacked to B-frag via pack + shfl_xor(32) pair-swap
//  - O' = mfma_32x32x16(A=Vt_frag, B=P_frag): C/D col = lane&31 = query,
//    so rescale/lsum stay lane-local.
//  - K/V read as 16B gathers from L2 (512KB per bh; grid keeps each bh on
//    one XCD: linear block id = qt*64 + bh -> id % 8 == bh % 8).

#define BATCH 4
#define HEADS 16
#define SEQ   2048
#define DIM   64
#define EPS   1e-8f
#define LOG2E 1.44269504088896340736f

typedef short bf16x8 __attribute__((ext_vector_type(8)));
typedef short s16x4  __attribute__((ext_vector_type(4)));
typedef float fx16   __attribute__((ext_vector_type(16)));
typedef unsigned int u32x4 __attribute__((ext_vector_type(4)));

static __device__ __forceinline__ short f2bf(float x) {
    unsigned u = __float_as_uint(x);
    unsigned r = (u + 0x7fffu + ((u >> 16) & 1u)) >> 16;   // RNE
    return (short)r;
}
static __device__ __forceinline__ unsigned pk_bf16(float a, float b) {
    return (unsigned)(unsigned short)f2bf(a) |
           ((unsigned)(unsigned short)f2bf(b) << 16);
}

// ---------------------------------------------------------------------------
// Kernel 1: row L2-normalize Q (scaled by g[h]) and K into bf16.
// ---------------------------------------------------------------------------
__global__ __launch_bounds__(256) void norm_rows(
    const float* __restrict__ Q, const float* __restrict__ K,
    const float* __restrict__ scale,
    short* __restrict__ Qn, short* __restrict__ Kn)
{
    const int tid  = threadIdx.x;
    const int lane = tid & 63;
    const long long R = (long long)BATCH * HEADS * SEQ;
    long long rid = (long long)blockIdx.x * 16 + (tid >> 6) * 4 + (lane >> 4);
    const int c4 = (lane & 15) * 4;

    const float* src;
    short* dst;
    float g;
    if (rid < R) {
        src = Q + rid * DIM;
        dst = Qn + rid * DIM;
        g = scale[(int)((rid >> 11) & (HEADS - 1))];
    } else {
        long long r2 = rid - R;
        src = K + r2 * DIM;
        dst = Kn + r2 * DIM;
        g = 1.0f;
    }

    float4 v = *(const float4*)(src + c4);
    float ss = v.x * v.x + v.y * v.y + v.z * v.z + v.w * v.w;
    ss += __shfl_xor(ss, 1);
    ss += __shfl_xor(ss, 2);
    ss += __shfl_xor(ss, 4);
    ss += __shfl_xor(ss, 8);
    float s = g / (sqrtf(ss) + EPS);

    s16x4 o;
    o[0] = f2bf(v.x * s);
    o[1] = f2bf(v.y * s);
    o[2] = f2bf(v.z * s);
    o[3] = f2bf(v.w * s);
    *(s16x4*)(dst + c4) = o;
}

// ---------------------------------------------------------------------------
// Kernel 2: V [n][d] fp32 -> Vt [d][n] bf16 per (b,h).
// ---------------------------------------------------------------------------
#define TLDS 68

__global__ __launch_bounds__(256) void transpose_v(
    const float* __restrict__ V, short* __restrict__ Vt)
{
    const int nt = blockIdx.x;
    const int bh = blockIdx.y;
    const float* Vb = V + ((size_t)bh * SEQ + (size_t)nt * 64) * DIM;
    short* Vo = Vt + (size_t)bh * DIM * SEQ + (size_t)nt * 64;

    __shared__ short lds[DIM * TLDS];
    const int t  = threadIdx.x;
    const int cg = t & 15;
    const int rr = t >> 4;

#pragma unroll
    for (int i = 0; i < 4; ++i) {
        int n  = rr + i * 16;
        int d0 = cg * 4;
        float4 v = *(const float4*)(Vb + (size_t)n * DIM + d0);
        lds[(d0 + 0) * TLDS + n] = f2bf(v.x);
        lds[(d0 + 1) * TLDS + n] = f2bf(v.y);
        lds[(d0 + 2) * TLDS + n] = f2bf(v.z);
        lds[(d0 + 3) * TLDS + n] = f2bf(v.w);
    }
    __syncthreads();
#pragma unroll
    for (int i = 0; i < 4; ++i) {
        int d  = rr + i * 16;
        int nl = cg * 4;
        s16x4 o;
        o[0] = lds[d * TLDS + nl + 0];
        o[1] = lds[d * TLDS + nl + 1];
        o[2] = lds[d * TLDS + nl + 2];
        o[3] = lds[d * TLDS + nl + 3];
        *(s16x4*)(Vo + (size_t)d * SEQ + nl) = o;
    }
}

// ---------------------------------------------------------------------------
// Kernel 3: causal flash attention, 1 wave per 32 query rows, no LDS.
//
// mfma_f32_32x32x16_bf16 layouts:
//   A: row = lane&31, k = (lane>>5)*8 + j      (j = 0..7)
//   B: col = lane&31, k = (lane>>5)*8 + j
//   C/D: col = lane&31, row = (reg&3) + 8*(reg>>2) + 4*(lane>>5)
//
// QK^T (swapped): S'[key][q] = mfma(A=K rows, B=Q rows-as-cols)
//   -> lane holds P[crow(reg,hi)][q=lane&31] for 2 key-tiles (32 f32).
// PV  (swapped): O'[d][q] = mfma(A=Vt rows, B=P)
//   -> oacc[dt][reg] = O[q=lane&31][d=dt*32+crow(reg,hi)]  (q lane-local!)
// ---------------------------------------------------------------------------
__global__ __launch_bounds__(64) void attn_fwd(
    const short* __restrict__ Qn, const short* __restrict__ Kn,
    const short* __restrict__ Vt, float* __restrict__ out)
{
    const int bh = blockIdx.x;
    const int qt = (gridDim.y - 1) - blockIdx.y;   // heavy tiles dispatched first
    const int l  = threadIdx.x;
    const int lq = l & 31;
    const int hi = l >> 5;

    const short* Qb = Qn + (size_t)bh * SEQ * DIM;
    const short* Kb = Kn + (size_t)bh * SEQ * DIM;
    const short* Vb = Vt + (size_t)bh * DIM * SEQ;

    const int qrow = qt * 32 + lq;

    // Q as B-operand: qb[c][j] = Q[qrow][c*16 + hi*8 + j]
    bf16x8 qb[4];
#pragma unroll
    for (int c = 0; c < 4; ++c)
        qb[c] = *(const bf16x8*)(Qb + (size_t)qrow * DIM + c * 16 + hi * 8);

    fx16 oacc[2];
#pragma unroll
    for (int dt = 0; dt < 2; ++dt)
#pragma unroll
        for (int r = 0; r < 16; ++r) oacc[dt][r] = 0.f;
    float m_run = -3.0e38f, lsum = 0.f;

    const int nkt = (qt >> 1) + 1;   // ceil(32*(qt+1)/64)

    for (int kt = 0; kt < nkt; ++kt) {
        const int k0 = kt * 64;

        // ---- S' = K x Q^T : two 32x32 key-tiles ----
        fx16 sacc[2];
#pragma unroll
        for (int t = 0; t < 2; ++t)
#pragma unroll
            for (int r = 0; r < 16; ++r) sacc[t][r] = 0.f;
#pragma unroll
        for (int c = 0; c < 4; ++c) {
            bf16x8 kf0 = *(const bf16x8*)(Kb + (size_t)(k0 + lq) * DIM + c * 16 + hi * 8);
            bf16x8 kf1 = *(const bf16x8*)(Kb + (size_t)(k0 + 32 + lq) * DIM + c * 16 + hi * 8);
            sacc[0] = __builtin_amdgcn_mfma_f32_32x32x16_bf16(kf0, qb[c], sacc[0], 0, 0, 0);
            sacc[1] = __builtin_amdgcn_mfma_f32_32x32x16_bf16(kf1, qb[c], sacc[1], 0, 0, 0);
        }

        float p[32];
#pragma unroll
        for (int t = 0; t < 2; ++t)
#pragma unroll
            for (int r = 0; r < 16; ++r) p[t * 16 + r] = sacc[t][r];

        // ---- causal mask: only the last tile crosses the diagonal ----
        if (kt == nkt - 1) {
#pragma unroll
            for (int t = 0; t < 2; ++t)
#pragma unroll
                for (int r = 0; r < 16; ++r) {
                    int key = k0 + 32 * t + (r & 3) + 8 * (r >> 2) + 4 * hi;
                    if (key > qrow) p[t * 16 + r] = -3.0e38f;
                }
        }

        // ---- row max (tree over 32 local + partner lane) ----
        float tm[16];
#pragma unroll
        for (int r = 0; r < 16; ++r) tm[r] = fmaxf(p[r], p[r + 16]);
#pragma unroll
        for (int r = 0; r < 8; ++r) tm[r] = fmaxf(tm[r], tm[r + 8]);
#pragma unroll
        for (int r = 0; r < 4; ++r) tm[r] = fmaxf(tm[r], tm[r + 4]);
        float mx = fmaxf(fmaxf(tm[0], tm[1]), fmaxf(tm[2], tm[3]));
        mx = fmaxf(mx, __shfl_xor(mx, 32));

        // ---- defer-max online softmax ----
        if (!__all(mx <= m_run + 8.0f)) {
            float mnew = fmaxf(m_run, mx);
            float sc = __builtin_amdgcn_exp2f((m_run - mnew) * LOG2E);
            m_run = mnew;
            lsum *= sc;
#pragma unroll
            for (int dt = 0; dt < 2; ++dt)
#pragma unroll
                for (int r = 0; r < 16; ++r) oacc[dt][r] *= sc;
        }
#pragma unroll
        for (int r = 0; r < 32; ++r)
            p[r] = __builtin_amdgcn_exp2f((p[r] - m_run) * LOG2E);
        float ts[16];
#pragma unroll
        for (int r = 0; r < 16; ++r) ts[r] = p[r] + p[r + 16];
#pragma unroll
        for (int r = 0; r < 8; ++r) ts[r] += ts[r + 8];
#pragma unroll
        for (int r = 0; r < 4; ++r) ts[r] += ts[r + 4];
        float ps = (ts[0] + ts[1]) + (ts[2] + ts[3]);
        ps += __shfl_xor(ps, 32);
        lsum += ps;

        // ---- repack P -> B-fragments (pair-swap across lane^32) ----
        // pa[ks] element j = bf16(P[key = k0 + 16*ks + 8*hi + j][q])
        u32x4 paw[4];
#pragma unroll
        for (int ks = 0; ks < 4; ++ks) {
            const int t = ks >> 1;
            const int b0 = (ks & 1) * 8;
#pragma unroll
            for (int m = 0; m < 2; ++m) {
                unsigned a = pk_bf16(p[t * 16 + b0 + 2 * m], p[t * 16 + b0 + 2 * m + 1]);
                unsigned b = pk_bf16(p[t * 16 + b0 + 2 * m + 4], p[t * 16 + b0 + 2 * m + 5]);
                unsigned snd = hi ? a : b;
                unsigned u = __shfl_xor(snd, 32);
                paw[ks][m]     = hi ? u : a;
                paw[ks][m + 2] = hi ? b : u;
            }
        }

        // ---- O' += Vt x P ----
#pragma unroll
        for (int dt = 0; dt < 2; ++dt) {
#pragma unroll
            for (int ks = 0; ks < 4; ++ks) {
                bf16x8 vf = *(const bf16x8*)(Vb + (size_t)(dt * 32 + lq) * SEQ
                                             + k0 + ks * 16 + hi * 8);
                bf16x8 pa = __builtin_bit_cast(bf16x8, paw[ks]);
                oacc[dt] = __builtin_amdgcn_mfma_f32_32x32x16_bf16(vf, pa, oacc[dt], 0, 0, 0);
            }
        }
    }

    // ---- epilogue: out[q][d] = O'/lsum ; q = lane&31, d = dt*32+crow(reg,hi)
    float inv = 1.0f / lsum;
    size_t rb = ((size_t)bh * SEQ + (size_t)qrow) * DIM;
#pragma unroll
    for (int dt = 0; dt < 2; ++dt)
#pragma unroll
        for (int g4 = 0; g4 < 4; ++g4) {
            float4 o4;
            o4.x = oacc[dt][4 * g4 + 0] * inv;
            o4.y = oacc[dt][4 * g4 + 1] * inv;
            o4.z = oacc[dt][4 * g4 + 2] * inv;
            o4.w = oacc[dt][4 * g4 + 3] * inv;
            *(float4*)(out + rb + dt * 32 + 8 * g4 + 4 * hi) = o4;
        }
}

// ---------------------------------------------------------------------------
extern "C" void kernel_launch(void* const* d_in, const int* in_sizes, int n_in,
                              void* d_out, int out_size, void* d_ws, size_t ws_size,
                              hipStream_t stream)
{
    const float* Q  = (const float*)d_in[0];
    const float* K  = (const float*)d_in[1];
    const float* V  = (const float*)d_in[2];
    const float* qs = (const float*)d_in[3];
    float* out = (float*)d_out;

    const size_t nElem = (size_t)BATCH * HEADS * SEQ * DIM;
    short* Qn = (short*)d_ws;
    short* Kn = Qn + nElem;
    short* Vt = Kn + nElem;

    {
        long long rows = 2LL * BATCH * HEADS * SEQ;
        norm_rows<<<(int)(rows / 16), 256, 0, stream>>>(Q, K, qs, Qn, Kn);
    }
    {
        dim3 grid(SEQ / 64, BATCH * HEADS);
        transpose_v<<<grid, 256, 0, stream>>>(V, Vt);
    }
    {
        // grid.x = bh (fast dim): all q-tiles of a bh share id%8 -> same XCD L2
        dim3 grid(BATCH * HEADS, SEQ / 32);
        attn_fwd<<<grid, 64, 0, stream>>>(Qn, Kn, Vt, out);
    }
}

// Round 3
// 152.552 us; speedup vs baseline: 1.6602x; 1.0206x over previous
//
#include <hip/hip_runtime.h>

// ScaledDotProductAttention: causal cosine attention.
// B=4 H=16 N=2048 D=64, fp32 in/out, bf16 MFMA compute.
//
// Round 3: no-max softmax (scores cosine-bounded: |s| <= g*log2e ~ 31.7, so
// p = exp2(s) directly -- exact by shift-invariance, no overflow possible),
// cvt_pk_bf16 repack, fused Q-norm, 4 balanced waves / 256-thread block.

#define BATCH 4
#define HEADS 16
#define SEQ   2048
#define DIM   64
#define EPS   1e-8f
#define LOG2E 1.44269504088896340736f

typedef short bf16x8 __attribute__((ext_vector_type(8)));
typedef short s16x4  __attribute__((ext_vector_type(4)));
typedef float fx16   __attribute__((ext_vector_type(16)));
typedef unsigned int u32x4 __attribute__((ext_vector_type(4)));

static __device__ __forceinline__ short f2bf(float x) {
    unsigned u = __float_as_uint(x);
    unsigned r = (u + 0x7fffu + ((u >> 16) & 1u)) >> 16;   // RNE
    return (short)r;
}
static __device__ __forceinline__ unsigned cvt_pk(float lo, float hi) {
    unsigned r;
    asm("v_cvt_pk_bf16_f32 %0, %1, %2" : "=v"(r) : "v"(lo), "v"(hi));
    return r;
}

// ---------------------------------------------------------------------------
// Kernel 1: K rows -> L2-normalized bf16.
// ---------------------------------------------------------------------------
__global__ __launch_bounds__(256) void norm_k(
    const float* __restrict__ K, short* __restrict__ Kn)
{
    const int tid  = threadIdx.x;
    const int lane = tid & 63;
    long long rid = (long long)blockIdx.x * 16 + (tid >> 6) * 4 + (lane >> 4);
    const int c4 = (lane & 15) * 4;

    const float* src = K + rid * DIM;
    short* dst = Kn + rid * DIM;

    float4 v = *(const float4*)(src + c4);
    float ss = v.x * v.x + v.y * v.y + v.z * v.z + v.w * v.w;
    ss += __shfl_xor(ss, 1);
    ss += __shfl_xor(ss, 2);
    ss += __shfl_xor(ss, 4);
    ss += __shfl_xor(ss, 8);
    float s = 1.0f / (sqrtf(ss) + EPS);

    s16x4 o;
    o[0] = f2bf(v.x * s);
    o[1] = f2bf(v.y * s);
    o[2] = f2bf(v.z * s);
    o[3] = f2bf(v.w * s);
    *(s16x4*)(dst + c4) = o;
}

// ---------------------------------------------------------------------------
// Kernel 2: V [n][d] fp32 -> Vt [d][n] bf16 per (b,h).
// ---------------------------------------------------------------------------
#define TLDS 68

__global__ __launch_bounds__(256) void transpose_v(
    const float* __restrict__ V, short* __restrict__ Vt)
{
    const int nt = blockIdx.x;
    const int bh = blockIdx.y;
    const float* Vb = V + ((size_t)bh * SEQ + (size_t)nt * 64) * DIM;
    short* Vo = Vt + (size_t)bh * DIM * SEQ + (size_t)nt * 64;

    __shared__ short lds[DIM * TLDS];
    const int t  = threadIdx.x;
    const int cg = t & 15;
    const int rr = t >> 4;

#pragma unroll
    for (int i = 0; i < 4; ++i) {
        int n  = rr + i * 16;
        int d0 = cg * 4;
        float4 v = *(const float4*)(Vb + (size_t)n * DIM + d0);
        lds[(d0 + 0) * TLDS + n] = f2bf(v.x);
        lds[(d0 + 1) * TLDS + n] = f2bf(v.y);
        lds[(d0 + 2) * TLDS + n] = f2bf(v.z);
        lds[(d0 + 3) * TLDS + n] = f2bf(v.w);
    }
    __syncthreads();
#pragma unroll
    for (int i = 0; i < 4; ++i) {
        int d  = rr + i * 16;
        int nl = cg * 4;
        s16x4 o;
        o[0] = lds[d * TLDS + nl + 0];
        o[1] = lds[d * TLDS + nl + 1];
        o[2] = lds[d * TLDS + nl + 2];
        o[3] = lds[d * TLDS + nl + 3];
        *(s16x4*)(Vo + (size_t)d * SEQ + nl) = o;
    }
}

// ---------------------------------------------------------------------------
// Kernel 3: causal flash attention, 256 threads = 4 independent waves,
// no LDS, no barriers. Wave w of block (bh, qg) handles q-tile
// qt in {qg, 31-qg, 32+qg, 63-qg}  -> every block = exactly 66 K-tiles.
//
// mfma_f32_32x32x16_bf16 layouts:
//   A: row = lane&31, k = (lane>>5)*8 + j
//   B: col = lane&31, k = (lane>>5)*8 + j
//   C/D: col = lane&31, row = (reg&3) + 8*(reg>>2) + 4*(lane>>5)
//
// Q is normalized in-kernel, scaled by g[h]*log2(e): scores land in
// log2-domain, p = exp2(s), no max subtraction needed (|s| <= 31.7).
// ---------------------------------------------------------------------------
__global__ __launch_bounds__(256) void attn_fwd(
    const float* __restrict__ Q, const float* __restrict__ scale,
    const short* __restrict__ Kn, const short* __restrict__ Vt,
    float* __restrict__ out)
{
    const int bh = blockIdx.x;
    const int qg = blockIdx.y;
    const int w  = threadIdx.x >> 6;
    const int l  = threadIdx.x & 63;
    const int lq = l & 31;
    const int hi = l >> 5;

    const int qt = (w == 0) ? qg : (w == 1) ? (31 - qg)
                 : (w == 2) ? (32 + qg) : (63 - qg);
    const int qrow = qt * 32 + lq;

    const short* Kb = Kn + (size_t)bh * SEQ * DIM;
    const short* Vb = Vt + (size_t)bh * DIM * SEQ;

    // ---- fused Q-norm: load this lane's half-row (32 dims), normalize ----
    const float* Qrow = Q + ((size_t)bh * SEQ + qrow) * DIM;
    float qv[4][8];
    float ss = 0.f;
#pragma unroll
    for (int c = 0; c < 4; ++c) {
        float4 a = *(const float4*)(Qrow + c * 16 + hi * 8);
        float4 b = *(const float4*)(Qrow + c * 16 + hi * 8 + 4);
        qv[c][0] = a.x; qv[c][1] = a.y; qv[c][2] = a.z; qv[c][3] = a.w;
        qv[c][4] = b.x; qv[c][5] = b.y; qv[c][6] = b.z; qv[c][7] = b.w;
#pragma unroll
        for (int j = 0; j < 8; ++j) ss += qv[c][j] * qv[c][j];
    }
    ss += __shfl_xor(ss, 32);                 // other half of the row
    const float g = scale[bh & (HEADS - 1)];
    const float sc = g * LOG2E / (sqrtf(ss) + EPS);

    // Q as B-operand: qb[c] word m = bf16x2(qv[c][2m], qv[c][2m+1])
    bf16x8 qb[4];
#pragma unroll
    for (int c = 0; c < 4; ++c) {
        u32x4 wds;
#pragma unroll
        for (int m = 0; m < 4; ++m)
            wds[m] = cvt_pk(qv[c][2 * m] * sc, qv[c][2 * m + 1] * sc);
        qb[c] = __builtin_bit_cast(bf16x8, wds);
    }

    fx16 oacc[2];
#pragma unroll
    for (int dt = 0; dt < 2; ++dt)
#pragma unroll
        for (int r = 0; r < 16; ++r) oacc[dt][r] = 0.f;
    float lsum = 0.f;

    const int nkt = (qt >> 1) + 1;

    for (int kt = 0; kt < nkt; ++kt) {
        const int k0 = kt * 64;

        // ---- S' = K x Q^T : two 32x32 key sub-tiles ----
        fx16 sacc[2];
#pragma unroll
        for (int t = 0; t < 2; ++t)
#pragma unroll
            for (int r = 0; r < 16; ++r) sacc[t][r] = 0.f;
#pragma unroll
        for (int c = 0; c < 4; ++c) {
            bf16x8 kf0 = *(const bf16x8*)(Kb + (size_t)(k0 + lq) * DIM + c * 16 + hi * 8);
            bf16x8 kf1 = *(const bf16x8*)(Kb + (size_t)(k0 + 32 + lq) * DIM + c * 16 + hi * 8);
            sacc[0] = __builtin_amdgcn_mfma_f32_32x32x16_bf16(kf0, qb[c], sacc[0], 0, 0, 0);
            sacc[1] = __builtin_amdgcn_mfma_f32_32x32x16_bf16(kf1, qb[c], sacc[1], 0, 0, 0);
        }

        // ---- V frags now: latency hidden under exp/repack VALU ----
        bf16x8 vf[2][4];
#pragma unroll
        for (int dt = 0; dt < 2; ++dt)
#pragma unroll
            for (int ks = 0; ks < 4; ++ks)
                vf[dt][ks] = *(const bf16x8*)(Vb + (size_t)(dt * 32 + lq) * SEQ
                                              + k0 + ks * 16 + hi * 8);

        float p[32];
#pragma unroll
        for (int t = 0; t < 2; ++t)
#pragma unroll
            for (int r = 0; r < 16; ++r) p[t * 16 + r] = sacc[t][r];

        // ---- causal mask: only the last K-tile crosses the diagonal ----
        if (kt == nkt - 1) {
#pragma unroll
            for (int t = 0; t < 2; ++t)
#pragma unroll
                for (int r = 0; r < 16; ++r) {
                    int key = k0 + 32 * t + (r & 3) + 8 * (r >> 2) + 4 * hi;
                    if (key > qrow) p[t * 16 + r] = -3.0e38f;
                }
        }

        // ---- p = exp2(s); no max shift needed (cosine-bounded scores) ----
#pragma unroll
        for (int r = 0; r < 32; ++r)
            p[r] = __builtin_amdgcn_exp2f(p[r]);

        // ---- lsum += row sum ----
        float ts[16];
#pragma unroll
        for (int r = 0; r < 16; ++r) ts[r] = p[r] + p[r + 16];
#pragma unroll
        for (int r = 0; r < 8; ++r) ts[r] += ts[r + 8];
#pragma unroll
        for (int r = 0; r < 4; ++r) ts[r] += ts[r + 4];
        float ps = (ts[0] + ts[1]) + (ts[2] + ts[3]);
        ps += __shfl_xor(ps, 32);
        lsum += ps;

        // ---- repack P -> B-fragments (pair-swap across lane^32) ----
        u32x4 paw[4];
#pragma unroll
        for (int ks = 0; ks < 4; ++ks) {
            const int t = ks >> 1;
            const int b0 = (ks & 1) * 8;
#pragma unroll
            for (int m = 0; m < 2; ++m) {
                unsigned a = cvt_pk(p[t * 16 + b0 + 2 * m], p[t * 16 + b0 + 2 * m + 1]);
                unsigned b = cvt_pk(p[t * 16 + b0 + 2 * m + 4], p[t * 16 + b0 + 2 * m + 5]);
                unsigned snd = hi ? a : b;
                unsigned u = __shfl_xor(snd, 32);
                paw[ks][m]     = hi ? u : a;
                paw[ks][m + 2] = hi ? b : u;
            }
        }

        // ---- O' += Vt x P ----
#pragma unroll
        for (int dt = 0; dt < 2; ++dt)
#pragma unroll
            for (int ks = 0; ks < 4; ++ks) {
                bf16x8 pa = __builtin_bit_cast(bf16x8, paw[ks]);
                oacc[dt] = __builtin_amdgcn_mfma_f32_32x32x16_bf16(vf[dt][ks], pa, oacc[dt], 0, 0, 0);
            }
    }

    // ---- epilogue: out[q][d] = O'/lsum ----
    float inv = 1.0f / lsum;
    size_t rb = ((size_t)bh * SEQ + (size_t)qrow) * DIM;
#pragma unroll
    for (int dt = 0; dt < 2; ++dt)
#pragma unroll
        for (int g4 = 0; g4 < 4; ++g4) {
            float4 o4;
            o4.x = oacc[dt][4 * g4 + 0] * inv;
            o4.y = oacc[dt][4 * g4 + 1] * inv;
            o4.z = oacc[dt][4 * g4 + 2] * inv;
            o4.w = oacc[dt][4 * g4 + 3] * inv;
            *(float4*)(out + rb + dt * 32 + 8 * g4 + 4 * hi) = o4;
        }
}

// ---------------------------------------------------------------------------
extern "C" void kernel_launch(void* const* d_in, const int* in_sizes, int n_in,
                              void* d_out, int out_size, void* d_ws, size_t ws_size,
                              hipStream_t stream)
{
    const float* Q  = (const float*)d_in[0];
    const float* K  = (const float*)d_in[1];
    const float* V  = (const float*)d_in[2];
    const float* qs = (const float*)d_in[3];
    float* out = (float*)d_out;

    const size_t nElem = (size_t)BATCH * HEADS * SEQ * DIM;
    short* Kn = (short*)d_ws;
    short* Vt = Kn + nElem;

    {
        long long rows = (long long)BATCH * HEADS * SEQ;
        norm_k<<<(int)(rows / 16), 256, 0, stream>>>(K, Kn);
    }
    {
        dim3 grid(SEQ / 64, BATCH * HEADS);
        transpose_v<<<grid, 256, 0, stream>>>(V, Vt);
    }
    {
        // grid.x = bh (fast dim): all q-tiles of a bh share id%8 -> same XCD L2
        dim3 grid(BATCH * HEADS, SEQ / 64 / 2);   // qg = 0..15
        attn_fwd<<<grid, 256, 0, stream>>>(Q, qs, Kn, Vt, out);
    }
}